// Round 1
// baseline (191.025 us; speedup 1.0000x reference)
//
#include <hip/hip_runtime.h>
#include <math.h>

// Problem constants
constexpr int Bb = 256;
constexpr int Ll = 512;
constexpr int Dd = 768;
constexpr int Pp = 30;
constexpr int Kk = 4;
constexpr int LOUT = Kk + Ll;          // 516
constexpr int D4   = Dd / 4;           // 192 float4 per row
constexpr int CHUNKS = 8;
constexpr int ROWS   = Ll / CHUNKS;    // 64 rows per chunk

// d_out layout (float elements): prompted_embedding, similarity, reduce_sim, idx(as float)
constexpr size_t PE_OFF  = 0;
constexpr size_t SIM_OFF = (size_t)Bb * LOUT * Dd;        // 101,449,728
constexpr size_t RS_OFF  = SIM_OFF + (size_t)Bb * Pp;     // +7680
constexpr size_t IDX_OFF = RS_OFF + 1;                    // +1

// d_ws layout (float elements)
constexpr size_t PART_OFF = 0;                            // B*CHUNKS*D partial sums
constexpr size_t PN_OFF   = (size_t)Bb * CHUNKS * Dd;     // 1,572,864: prompt_norm P*D
constexpr size_t RED_OFF  = PN_OFF + (size_t)Pp * Dd;     // +23,040: per-b reduce partial

// ---------------------------------------------------------------------------
// Kernel A: copy x_embed -> out[b, K+l, :] and accumulate per-chunk column sums.
// grid (CHUNKS, B), block 192 (3 waves). float4 everywhere: 192*16B = 3 KB/row.
__global__ void copy_mean_kernel(const float4* __restrict__ x,
                                 float4* __restrict__ out,
                                 float4* __restrict__ part) {
    const int c = blockIdx.x;            // chunk of L
    const int b = blockIdx.y;
    const int t = threadIdx.x;           // 0..191

    const float4* src = x   + (size_t)(b * Ll + c * ROWS) * D4 + t;
    float4*       dst = out + (size_t)(b * LOUT + Kk + c * ROWS) * D4 + t;

    float4 s = {0.f, 0.f, 0.f, 0.f};
#pragma unroll 4
    for (int l = 0; l < ROWS; ++l) {
        float4 v = src[(size_t)l * D4];
        dst[(size_t)l * D4] = v;
        s.x += v.x; s.y += v.y; s.z += v.z; s.w += v.w;
    }
    part[(size_t)(b * CHUNKS + c) * D4 + t] = s;
}

// ---------------------------------------------------------------------------
__device__ inline double block_reduce_sum(double v, double* smem) {
    // wave64 butterfly then cross-wave via LDS
    for (int off = 32; off > 0; off >>= 1) v += __shfl_down(v, off, 64);
    const int lane = threadIdx.x & 63;
    const int w    = threadIdx.x >> 6;
    if (lane == 0) smem[w] = v;
    __syncthreads();
    if (threadIdx.x == 0) {
        double s = 0.0;
        const int nw = (blockDim.x + 63) >> 6;
        for (int i = 0; i < nw; ++i) s += smem[i];
        smem[0] = s;
    }
    __syncthreads();
    double r = smem[0];
    __syncthreads();
    return r;
}

// Kernel B: prompt_norm[p,:] = prompt[p,:] * rsqrt(max(sum sq, eps)). 30 blocks x 256.
__global__ void prompt_norm_kernel(const float* __restrict__ prompt,
                                   float* __restrict__ pn) {
    __shared__ double smem[8];
    const int p = blockIdx.x;
    const int t = threadIdx.x;
    float v[3];
    double ss = 0.0;
#pragma unroll
    for (int i = 0; i < 3; ++i) {
        v[i] = prompt[p * Dd + t + i * 256];
        ss += (double)v[i] * (double)v[i];
    }
    ss = block_reduce_sum(ss, smem);
    const double rs = 1.0 / sqrt(fmax(ss, 1e-12));
#pragma unroll
    for (int i = 0; i < 3; ++i)
        pn[p * Dd + t + i * 256] = (float)((double)v[i] * rs);
}

// ---------------------------------------------------------------------------
// Kernel C: per-batch. Combine partials -> mean -> x_norm (LDS), 30 dots,
// top-4 (stable, lower index on ties), write similarity + idx(as float) +
// batched_prompt rows + per-b reduce_sim partial. 256 blocks x 256 threads.
__global__ void sim_topk_kernel(const float* __restrict__ part,
                                const float* __restrict__ pn,
                                const float* __restrict__ prompt,
                                float* __restrict__ out,
                                float* __restrict__ red) {
    __shared__ float  xn[Dd];
    __shared__ float  sims[Pp];
    __shared__ int    tidx[Kk];
    __shared__ double smem[8];

    const int b = blockIdx.x;
    const int t = threadIdx.x;

    // combine 8 chunk partials (double), mean, sum of squares
    double md[3];
    double ss = 0.0;
#pragma unroll
    for (int i = 0; i < 3; ++i) {
        const int d = t + i * 256;
        double s = 0.0;
#pragma unroll
        for (int c = 0; c < CHUNKS; ++c)
            s += (double)part[(size_t)(b * CHUNKS + c) * Dd + d];
        md[i] = s * (1.0 / Ll);
        ss += md[i] * md[i];
    }
    ss = block_reduce_sum(ss, smem);
    const double rs = 1.0 / sqrt(fmax(ss, 1e-12));
#pragma unroll
    for (int i = 0; i < 3; ++i)
        xn[t + i * 256] = (float)(md[i] * rs);
    __syncthreads();

    // similarity: 8 lanes per prompt, 240 active threads
    if (t < Pp * 8) {
        const int p = t >> 3;
        const int g = t & 7;
        double acc = 0.0;
        for (int i = g; i < Dd; i += 8)
            acc += (double)xn[i] * (double)pn[p * Dd + i];
#pragma unroll
        for (int off = 4; off > 0; off >>= 1)
            acc += __shfl_down(acc, off, 8);
        if (g == 0) {
            const float sv = (float)acc;
            sims[p] = sv;
            out[SIM_OFF + (size_t)b * Pp + p] = sv;
        }
    }
    __syncthreads();

    // top-4 (strict > keeps earliest index on ties, matching lax.top_k)
    if (t == 0) {
        float sv[Pp];
        for (int p = 0; p < Pp; ++p) sv[p] = sims[p];
        double rsum = 0.0;
        for (int k = 0; k < Kk; ++k) {
            float best = -INFINITY;
            int   bi   = 0;
            for (int p = 0; p < Pp; ++p) {
                if (sv[p] > best) { best = sv[p]; bi = p; }
            }
            tidx[k] = bi;
            out[IDX_OFF + (size_t)b * Kk + k] = (float)bi;
            rsum += (double)best;
            sv[bi] = -INFINITY;
        }
        red[b] = (float)rsum;
    }
    __syncthreads();

    // batched_prompt: out[b, k, :] = prompt[tidx[k], :]   (raw prompt rows)
    const float4* pr4 = (const float4*)prompt;
    float4*       o4  = (float4*)out;
    for (int j = t; j < Kk * D4; j += 256) {
        const int k   = j / D4;
        const int col = j % D4;
        o4[(size_t)(b * LOUT + k) * D4 + col] = pr4[(size_t)tidx[k] * D4 + col];
    }
}

// ---------------------------------------------------------------------------
// Kernel D: reduce_sim = sum_b red[b] / B. 1 block x 256.
__global__ void finalize_kernel(const float* __restrict__ red,
                                float* __restrict__ out) {
    __shared__ double smem[8];
    double v = (double)red[threadIdx.x];
    v = block_reduce_sum(v, smem);
    if (threadIdx.x == 0)
        out[RS_OFF] = (float)(v * (1.0 / Bb));
}

// ---------------------------------------------------------------------------
extern "C" void kernel_launch(void* const* d_in, const int* in_sizes, int n_in,
                              void* d_out, int out_size, void* d_ws, size_t ws_size,
                              hipStream_t stream) {
    const float* x_embed = (const float*)d_in[0];   // [256,512,768]
    const float* prompt  = (const float*)d_in[1];   // [30,768]
    float* out = (float*)d_out;
    float* ws  = (float*)d_ws;

    float* part = ws + PART_OFF;
    float* pn   = ws + PN_OFF;
    float* red  = ws + RED_OFF;

    // A: copy + partial mean
    copy_mean_kernel<<<dim3(CHUNKS, Bb), 192, 0, stream>>>(
        (const float4*)x_embed, (float4*)out, (float4*)part);

    // B: prompt norm
    prompt_norm_kernel<<<Pp, 256, 0, stream>>>(prompt, pn);

    // C: per-batch sim + topk + gather
    sim_topk_kernel<<<Bb, 256, 0, stream>>>(part, pn, prompt, out, red);

    // D: reduce_sim
    finalize_kernel<<<1, 256, 0, stream>>>(red, out);
}

// Round 2
// 182.924 us; speedup vs baseline: 1.0443x; 1.0443x over previous
//
#include <hip/hip_runtime.h>
#include <math.h>

// Problem constants
constexpr int Bb = 256;
constexpr int Ll = 512;
constexpr int Dd = 768;
constexpr int Pp = 30;
constexpr int Kk = 4;
constexpr int LOUT = Kk + Ll;          // 516
constexpr int D4   = Dd / 4;           // 192 float4 per row
constexpr int CHUNKS = 8;
constexpr int ROWS   = Ll / CHUNKS;    // 64 rows per chunk

typedef float f32x4 __attribute__((ext_vector_type(4)));

// d_out layout (float elements): prompted_embedding, similarity, reduce_sim, idx(as float)
constexpr size_t PE_OFF  = 0;
constexpr size_t SIM_OFF = (size_t)Bb * LOUT * Dd;        // 101,449,728
constexpr size_t RS_OFF  = SIM_OFF + (size_t)Bb * Pp;     // +7680
constexpr size_t IDX_OFF = RS_OFF + 1;                    // +1

// d_ws layout (float elements)
constexpr size_t PART_OFF = 0;                            // B*CHUNKS*D partial sums
constexpr size_t RED_OFF  = (size_t)Bb * CHUNKS * Dd;     // per-b reduce partial

// ---------------------------------------------------------------------------
// Kernel A: copy x_embed -> out[b, K+l, :] and accumulate per-chunk column sums.
// grid (CHUNKS, B), block 192 (3 waves). Non-temporal float4 on both streams:
// 810 MB use-once data should not allocate in L2.
__global__ void copy_mean_kernel(const f32x4* __restrict__ x,
                                 f32x4* __restrict__ out,
                                 f32x4* __restrict__ part) {
    const int c = blockIdx.x;            // chunk of L
    const int b = blockIdx.y;
    const int t = threadIdx.x;           // 0..191

    const f32x4* src = x   + (size_t)(b * Ll + c * ROWS) * D4 + t;
    f32x4*       dst = out + (size_t)(b * LOUT + Kk + c * ROWS) * D4 + t;

    f32x4 s = {0.f, 0.f, 0.f, 0.f};
#pragma unroll 4
    for (int l = 0; l < ROWS; ++l) {
        f32x4 v = __builtin_nontemporal_load(src + (size_t)l * D4);
        __builtin_nontemporal_store(v, dst + (size_t)l * D4);
        s += v;
    }
    part[(size_t)(b * CHUNKS + c) * D4 + t] = s;
}

// ---------------------------------------------------------------------------
__device__ inline double block_reduce_sum(double v, double* smem) {
    for (int off = 32; off > 0; off >>= 1) v += __shfl_down(v, off, 64);
    const int lane = threadIdx.x & 63;
    const int w    = threadIdx.x >> 6;
    if (lane == 0) smem[w] = v;
    __syncthreads();
    if (threadIdx.x == 0) {
        double s = 0.0;
        const int nw = (blockDim.x + 63) >> 6;
        for (int i = 0; i < nw; ++i) s += smem[i];
        smem[0] = s;
    }
    __syncthreads();
    double r = smem[0];
    __syncthreads();
    return r;
}

// ---------------------------------------------------------------------------
// Kernel C: per-batch. Combine partials -> mean -> x_norm (LDS); 30 fused
// dot+prompt-norm (8 lanes/prompt); top-4 (strict >, earliest index on ties);
// write similarity, idx (as float), batched_prompt rows, reduce_sim partial.
__global__ void sim_topk_kernel(const float* __restrict__ part,
                                const float* __restrict__ prompt,
                                float* __restrict__ out,
                                float* __restrict__ red) {
    __shared__ float  xn[Dd];
    __shared__ float  sims[Pp];
    __shared__ int    tidx[Kk];
    __shared__ double smem[8];

    const int b = blockIdx.x;
    const int t = threadIdx.x;

    // combine 8 chunk partials (double), mean, sum of squares
    double md[3];
    double ss = 0.0;
#pragma unroll
    for (int i = 0; i < 3; ++i) {
        const int d = t + i * 256;
        double s = 0.0;
#pragma unroll
        for (int c = 0; c < CHUNKS; ++c)
            s += (double)part[(size_t)(b * CHUNKS + c) * Dd + d];
        md[i] = s * (1.0 / Ll);
        ss += md[i] * md[i];
    }
    ss = block_reduce_sum(ss, smem);
    const double rs = 1.0 / sqrt(fmax(ss, 1e-12));
#pragma unroll
    for (int i = 0; i < 3; ++i)
        xn[t + i * 256] = (float)(md[i] * rs);
    __syncthreads();

    // similarity with fused prompt normalization: 8 lanes per prompt
    if (t < Pp * 8) {
        const int p = t >> 3;
        const int g = t & 7;
        double dot = 0.0, pss = 0.0;
        for (int i = g; i < Dd; i += 8) {
            const double pv = (double)prompt[p * Dd + i];
            dot += (double)xn[i] * pv;
            pss += pv * pv;
        }
#pragma unroll
        for (int off = 4; off > 0; off >>= 1) {
            dot += __shfl_down(dot, off, 8);
            pss += __shfl_down(pss, off, 8);
        }
        if (g == 0) {
            const float sv = (float)(dot / sqrt(fmax(pss, 1e-12)));
            sims[p] = sv;
            out[SIM_OFF + (size_t)b * Pp + p] = sv;
        }
    }
    __syncthreads();

    // top-4 (strict > keeps earliest index on ties, matching lax.top_k)
    if (t == 0) {
        float sv[Pp];
        for (int p = 0; p < Pp; ++p) sv[p] = sims[p];
        double rsum = 0.0;
        for (int k = 0; k < Kk; ++k) {
            float best = -INFINITY;
            int   bi   = 0;
            for (int p = 0; p < Pp; ++p) {
                if (sv[p] > best) { best = sv[p]; bi = p; }
            }
            tidx[k] = bi;
            out[IDX_OFF + (size_t)b * Kk + k] = (float)bi;
            rsum += (double)best;
            sv[bi] = -INFINITY;
        }
        red[b] = (float)rsum;
    }
    __syncthreads();

    // batched_prompt: out[b, k, :] = prompt[tidx[k], :]   (raw prompt rows)
    const f32x4* pr4 = (const f32x4*)prompt;
    f32x4*       o4  = (f32x4*)out;
    for (int j = t; j < Kk * D4; j += 256) {
        const int k   = j / D4;
        const int col = j % D4;
        o4[(size_t)(b * LOUT + k) * D4 + col] = pr4[(size_t)tidx[k] * D4 + col];
    }
}

// ---------------------------------------------------------------------------
// Kernel D: reduce_sim = sum_b red[b] / B. 1 block x 256.
__global__ void finalize_kernel(const float* __restrict__ red,
                                float* __restrict__ out) {
    __shared__ double smem[8];
    double v = (double)red[threadIdx.x];
    v = block_reduce_sum(v, smem);
    if (threadIdx.x == 0)
        out[RS_OFF] = (float)(v * (1.0 / Bb));
}

// ---------------------------------------------------------------------------
extern "C" void kernel_launch(void* const* d_in, const int* in_sizes, int n_in,
                              void* d_out, int out_size, void* d_ws, size_t ws_size,
                              hipStream_t stream) {
    const float* x_embed = (const float*)d_in[0];   // [256,512,768]
    const float* prompt  = (const float*)d_in[1];   // [30,768]
    float* out = (float*)d_out;
    float* ws  = (float*)d_ws;

    float* part = ws + PART_OFF;
    float* red  = ws + RED_OFF;

    // A: copy + partial mean (the 810 MB streaming kernel)
    copy_mean_kernel<<<dim3(CHUNKS, Bb), 192, 0, stream>>>(
        (const f32x4*)x_embed, (f32x4*)out, (f32x4*)part);

    // C: per-batch sim + topk + gather (prompt norm fused in)
    sim_topk_kernel<<<Bb, 256, 0, stream>>>(part, prompt, out, red);

    // D: reduce_sim
    finalize_kernel<<<1, 256, 0, stream>>>(red, out);
}

// Round 3
// 174.763 us; speedup vs baseline: 1.0931x; 1.0467x over previous
//
#include <hip/hip_runtime.h>
#include <math.h>

// Problem constants
constexpr int Bb = 256;
constexpr int Ll = 512;
constexpr int Dd = 768;
constexpr int Pp = 30;
constexpr int Kk = 4;
constexpr int LOUT = Kk + Ll;          // 516
constexpr int D4   = Dd / 4;           // 192 float4 per row
constexpr int CHUNKS = 16;             // 16 chunks -> 4096 blocks -> 30 waves/CU
constexpr int ROWS   = Ll / CHUNKS;    // 32 rows per chunk

typedef float f32x4 __attribute__((ext_vector_type(4)));

// d_out layout (float elements): prompted_embedding, similarity, reduce_sim, idx(as float)
constexpr size_t PE_OFF  = 0;
constexpr size_t SIM_OFF = (size_t)Bb * LOUT * Dd;        // 101,449,728
constexpr size_t RS_OFF  = SIM_OFF + (size_t)Bb * Pp;     // +7680
constexpr size_t IDX_OFF = RS_OFF + 1;                    // +1

// d_ws layout (float elements)
constexpr size_t PART_OFF = 0;                            // B*CHUNKS*D partial sums
constexpr size_t RED_OFF  = (size_t)Bb * CHUNKS * Dd;     // per-b reduce partial

// ---------------------------------------------------------------------------
// Kernel A: copy x_embed -> out[b, K+l, :] and accumulate per-chunk column sums.
// grid (CHUNKS, B) = 4096 blocks, block 192 (3 waves, 10 blocks/CU = 30 waves).
// 8-deep load batches then 8 stores: doubles MLP, same-direction HBM bursts.
__global__ void copy_mean_kernel(const f32x4* __restrict__ x,
                                 f32x4* __restrict__ out,
                                 f32x4* __restrict__ part) {
    const int c = blockIdx.x;            // chunk of L
    const int b = blockIdx.y;
    const int t = threadIdx.x;           // 0..191

    const f32x4* src = x   + (size_t)(b * Ll + c * ROWS) * D4 + t;
    f32x4*       dst = out + (size_t)(b * LOUT + Kk + c * ROWS) * D4 + t;

    f32x4 s = {0.f, 0.f, 0.f, 0.f};
    for (int l0 = 0; l0 < ROWS; l0 += 8) {
        f32x4 v[8];
#pragma unroll
        for (int j = 0; j < 8; ++j)
            v[j] = __builtin_nontemporal_load(src + (size_t)(l0 + j) * D4);
#pragma unroll
        for (int j = 0; j < 8; ++j) {
            __builtin_nontemporal_store(v[j], dst + (size_t)(l0 + j) * D4);
            s += v[j];
        }
    }
    part[(size_t)(b * CHUNKS + c) * D4 + t] = s;
}

// ---------------------------------------------------------------------------
__device__ inline double block_reduce_sum(double v, double* smem) {
    for (int off = 32; off > 0; off >>= 1) v += __shfl_down(v, off, 64);
    const int lane = threadIdx.x & 63;
    const int w    = threadIdx.x >> 6;
    if (lane == 0) smem[w] = v;
    __syncthreads();
    if (threadIdx.x == 0) {
        double s = 0.0;
        const int nw = (blockDim.x + 63) >> 6;
        for (int i = 0; i < nw; ++i) s += smem[i];
        smem[0] = s;
    }
    __syncthreads();
    double r = smem[0];
    __syncthreads();
    return r;
}

// ---------------------------------------------------------------------------
// Kernel C: per-batch. Combine partials -> mean -> x_norm (LDS); 30 fused
// dot+prompt-norm (8 lanes/prompt); top-4 (strict >, earliest index on ties);
// write similarity, idx (as float), batched_prompt rows, reduce_sim partial.
__global__ void sim_topk_kernel(const float* __restrict__ part,
                                const float* __restrict__ prompt,
                                float* __restrict__ out,
                                float* __restrict__ red) {
    __shared__ float  xn[Dd];
    __shared__ float  sims[Pp];
    __shared__ int    tidx[Kk];
    __shared__ double smem[8];

    const int b = blockIdx.x;
    const int t = threadIdx.x;

    // combine chunk partials (double), mean, sum of squares
    double md[3];
    double ss = 0.0;
#pragma unroll
    for (int i = 0; i < 3; ++i) {
        const int d = t + i * 256;
        double s = 0.0;
#pragma unroll
        for (int c = 0; c < CHUNKS; ++c)
            s += (double)part[(size_t)(b * CHUNKS + c) * Dd + d];
        md[i] = s * (1.0 / Ll);
        ss += md[i] * md[i];
    }
    ss = block_reduce_sum(ss, smem);
    const double rs = 1.0 / sqrt(fmax(ss, 1e-12));
#pragma unroll
    for (int i = 0; i < 3; ++i)
        xn[t + i * 256] = (float)(md[i] * rs);
    __syncthreads();

    // similarity with fused prompt normalization: 8 lanes per prompt
    if (t < Pp * 8) {
        const int p = t >> 3;
        const int g = t & 7;
        double dot = 0.0, pss = 0.0;
        for (int i = g; i < Dd; i += 8) {
            const double pv = (double)prompt[p * Dd + i];
            dot += (double)xn[i] * pv;
            pss += pv * pv;
        }
#pragma unroll
        for (int off = 4; off > 0; off >>= 1) {
            dot += __shfl_down(dot, off, 8);
            pss += __shfl_down(pss, off, 8);
        }
        if (g == 0) {
            const float sv = (float)(dot / sqrt(fmax(pss, 1e-12)));
            sims[p] = sv;
            out[SIM_OFF + (size_t)b * Pp + p] = sv;
        }
    }
    __syncthreads();

    // top-4 (strict > keeps earliest index on ties, matching lax.top_k)
    if (t == 0) {
        float sv[Pp];
        for (int p = 0; p < Pp; ++p) sv[p] = sims[p];
        double rsum = 0.0;
        for (int k = 0; k < Kk; ++k) {
            float best = -INFINITY;
            int   bi   = 0;
            for (int p = 0; p < Pp; ++p) {
                if (sv[p] > best) { best = sv[p]; bi = p; }
            }
            tidx[k] = bi;
            out[IDX_OFF + (size_t)b * Kk + k] = (float)bi;
            rsum += (double)best;
            sv[bi] = -INFINITY;
        }
        red[b] = (float)rsum;
    }
    __syncthreads();

    // batched_prompt: out[b, k, :] = prompt[tidx[k], :]   (raw prompt rows)
    const f32x4* pr4 = (const f32x4*)prompt;
    f32x4*       o4  = (f32x4*)out;
    for (int j = t; j < Kk * D4; j += 256) {
        const int k   = j / D4;
        const int col = j % D4;
        o4[(size_t)(b * LOUT + k) * D4 + col] = pr4[(size_t)tidx[k] * D4 + col];
    }
}

// ---------------------------------------------------------------------------
// Kernel D: reduce_sim = sum_b red[b] / B. 1 block x 256.
__global__ void finalize_kernel(const float* __restrict__ red,
                                float* __restrict__ out) {
    __shared__ double smem[8];
    double v = (double)red[threadIdx.x];
    v = block_reduce_sum(v, smem);
    if (threadIdx.x == 0)
        out[RS_OFF] = (float)(v * (1.0 / Bb));
}

// ---------------------------------------------------------------------------
extern "C" void kernel_launch(void* const* d_in, const int* in_sizes, int n_in,
                              void* d_out, int out_size, void* d_ws, size_t ws_size,
                              hipStream_t stream) {
    const float* x_embed = (const float*)d_in[0];   // [256,512,768]
    const float* prompt  = (const float*)d_in[1];   // [30,768]
    float* out = (float*)d_out;
    float* ws  = (float*)d_ws;

    float* part = ws + PART_OFF;
    float* red  = ws + RED_OFF;

    // A: copy + partial mean (the 810 MB streaming kernel)
    copy_mean_kernel<<<dim3(CHUNKS, Bb), 192, 0, stream>>>(
        (const f32x4*)x_embed, (f32x4*)out, (f32x4*)part);

    // C: per-batch sim + topk + gather (prompt norm fused in)
    sim_topk_kernel<<<Bb, 256, 0, stream>>>(part, prompt, out, red);

    // D: reduce_sim
    finalize_kernel<<<1, 256, 0, stream>>>(red, out);
}